// Round 13
// baseline (3321.689 us; speedup 1.0000x reference)
//
#include <hip/hip_runtime.h>

#define TT 1024
#define BB 256
#define HH 512
#define G4 2048
#define NG 32   // sample groups
#define SG 8    // samples per group
#define NJ 16   // wgs (j-slices) per cohort
#define RW 128  // rows per slice = 4 gates * 32 j
#define JW 32   // j per slice
#define GXN 131072  // 2 * 256 * 256 exchange units (8B each)

typedef _Float16 half2v __attribute__((ext_vector_type(2)));
typedef _Float16 half8  __attribute__((ext_vector_type(8)));
typedef float    f32x4  __attribute__((ext_vector_type(4)));
typedef unsigned int uint;
typedef unsigned long long u64t;

union U32H  { uint u; half2v h; };
union U128H { uint4 u; half8 h; };

// ---------------- prep: fp16 W repack into MFMA A-fragments + gx clear ------
// m = jjq*4 + gate (jj-major, gate-minor) so a lane's 4 D-regs are i,f,g,o of ONE jj.
__global__ __launch_bounds__(256) void prep_k(
    const float* __restrict__ Whh, const float* __restrict__ fcW,
    const float* __restrict__ bih, const float* __restrict__ bhh,
    uint* __restrict__ Wpk16, float* __restrict__ fcWT, float* __restrict__ bsum,
    u64t* __restrict__ gx)
{
    int n  = blockDim.x * gridDim.x;
    int i0 = blockIdx.x * blockDim.x + threadIdx.x;
    for (int i = i0; i < NJ * 8 * 16 * 64 * 4; i += n) {
        int d  = i & 3;
        int l  = (i >> 2) & 63;
        int kk = (i >> 8) & 15;
        int w  = (i >> 12) & 7;
        int jg = (i >> 15) & 15;
        int m    = l & 15;
        int gate = m & 3, jjq = m >> 2;
        int grow = gate * HH + jg * JW + w * 4 + jjq;
        int k    = kk * 32 + ((l >> 4) & 3) * 8 + 2 * d;
        half2v p;
        p.x = (_Float16)Whh[grow * HH + k];
        p.y = (_Float16)Whh[grow * HH + k + 1];
        U32H x; x.h = p;
        Wpk16[i] = x.u;
    }
    for (int i = i0; i < HH * TT; i += n) {
        int k = i >> 10, t = i & (TT - 1);
        fcWT[i] = fcW[t * HH + k];
    }
    for (int i = i0; i < G4; i += n) bsum[i] = bih[i] + bhh[i];
    for (int i = i0; i < GXN; i += n) gx[i] = 0;   // clear tags EVERY launch
}

// ---------------- lengths ----------------
__global__ __launch_bounds__(256) void lens_k(const float* __restrict__ traj,
                                              int* __restrict__ len)
{
    int b = blockIdx.x;
    int cnt = 0;
    for (int i = threadIdx.x; i < TT; i += 256)
        cnt += (traj[b * TT + i] != -1.0f) ? 1 : 0;
    for (int o = 32; o > 0; o >>= 1) cnt += __shfl_down(cnt, o, 64);
    __shared__ int s4[4];
    if ((threadIdx.x & 63) == 0) s4[threadIdx.x >> 6] = cnt;
    __syncthreads();
    if (threadIdx.x == 0) len[b] = s4[0] + s4[1] + s4[2] + s4[3];
}

// ---------------- sort by length (descending), group maxes ----------------
__global__ __launch_bounds__(256) void sort_k(const int* __restrict__ len,
                                              int* __restrict__ perm,
                                              int* __restrict__ glen)
{
    __shared__ int L[256];
    __shared__ int P[256];
    int tid = threadIdx.x;
    L[tid] = len[tid];
    __syncthreads();
    int l = L[tid], r = 0;
    for (int b = 0; b < 256; ++b) {
        int lb = L[b];
        r += (lb > l) || (lb == l && b < tid);
    }
    P[r] = tid;
    __syncthreads();
    perm[tid] = P[tid];
    if (tid < NG) glen[tid] = L[P[tid * SG]];
}

// ---------------- persistent LSTM: tagged units, direct-from-lane produce ---
// grid 256 = 16 slots x 16 j-slices. Slot p serves groups gA=p (cols 0-7) and
// gB=31-p (cols 8-15) in one MFMA pass. Exchange unit = {2 fp16 h | tag} u64,
// agent-scope atomics; producers store straight from gate lanes via shfl_xor.
__global__ __launch_bounds__(512, 2) void lstm_persist(
    const float* __restrict__ traj, const float* __restrict__ Wih,
    const uint* __restrict__ Wpk16, const float* __restrict__ bsum,
    float* __restrict__ hbuf,                 // [BB][HH] final h only
    u64t* __restrict__ gx,                    // [2][256][256] tagged units
    const int* __restrict__ perm, const int* __restrict__ glen)
{
    __shared__ __align__(16) float smem[23040];   // 90KB -> 1 wg/CU
    __shared__ float xsm[16], mkm[16];
    __shared__ int   osm[16];
    __shared__ float wih_s[RW], bsum_s[RW];

    uint* const hs16 = (uint*)smem;               // 16 x 256 dw

    const int wg   = blockIdx.x;
    const int slot = wg & 15;
    const int jg   = wg >> 4;
    const int tid  = threadIdx.x;
    const int gA = slot, gB = 31 - slot;

    if (tid < 16)
        osm[tid] = perm[(tid < 8) ? (gA * SG + tid) : (gB * SG + tid - 8)];
    if (tid < RW) {
        int m = tid & 15;
        int grow = (m & 3) * HH + jg * JW + (tid >> 4) * 4 + (m >> 2);
        wih_s[tid]  = Wih[grow];
        bsum_s[tid] = bsum[grow];
    }
    const int glenA = glen[gA];

    // W A-fragments -> registers
    half8 wf[16];
    {
        const int w0 = tid >> 6, l0 = tid & 63;
        const uint4* wp = (const uint4*)Wpk16;
        const int base = (jg * 8 + w0) * 1024 + l0;
        #pragma unroll
        for (int kk = 0; kk < 16; ++kk) {
            U128H u; u.u = wp[base + kk * 64];
            wf[kk] = u.h;
        }
    }

    // lane roles
    const int w   = tid >> 6;       // wave id
    const int l   = tid & 63;
    const int sm  = l & 15;         // MFMA column = sample slot (A:0-7, B:8-15)
    const int ks  = (l >> 4) & 3;
    const int jjl = w * 4 + ks;
    const int sslot = (sm < 8) ? (gA * SG + sm) : (gB * SG + sm - 8);
    const int csA = gA * SG + w;    // staging samples (consumer role)
    const int csB = gB * SG + w;
    const int swz = (w & 7) << 2;
    // producer role: even-ks lanes store unit (sslot, jg*16 + w*2 + (ks>>1))
    const int myk2 = jg * 16 + w * 2 + (ks >> 1);

    float creg = 0.f, hreg = 0.f;
    __syncthreads();

    for (int t = 0; t < glenA; ++t) {
        // ---- early x loads (complete under the poll) ----
        if (tid < 16) {
            float v = traj[(size_t)osm[tid] * TT + t];
            xsm[tid] = v;
            mkm[tid] = (v != -1.0f) ? 1.f : 0.f;
        }
        // ---- stage h(t) -> LDS (fp16 pairs, XOR-swizzled dword pairs) ----
        if (t == 0) {
            u64t z = 0;
            *(u64t*)&hs16[w * 256 + ((2 * l) ^ swz)]             = z;
            *(u64t*)&hs16[w * 256 + ((2 * l + 128) ^ swz)]       = z;
            *(u64t*)&hs16[(w + 8) * 256 + ((2 * l) ^ swz)]       = z;
            *(u64t*)&hs16[(w + 8) * 256 + ((2 * l + 128) ^ swz)] = z;
        } else {
            u64t* base = gx + (size_t)(t & 1) * 65536;
            u64t* pa = base + (size_t)csA * 256 + 2 * l;
            u64t* pb = base + (size_t)csB * 256 + 2 * l;
            const uint tg = (uint)t;
            u64t v0, v1, v2, v3, v4, v5, v6, v7;
            int cap = 1 << 22;           // bounded spin: never hang
            for (;;) {
                v0 = __hip_atomic_load(pa,       __ATOMIC_RELAXED, __HIP_MEMORY_SCOPE_AGENT);
                v1 = __hip_atomic_load(pa + 1,   __ATOMIC_RELAXED, __HIP_MEMORY_SCOPE_AGENT);
                v2 = __hip_atomic_load(pa + 128, __ATOMIC_RELAXED, __HIP_MEMORY_SCOPE_AGENT);
                v3 = __hip_atomic_load(pa + 129, __ATOMIC_RELAXED, __HIP_MEMORY_SCOPE_AGENT);
                v4 = __hip_atomic_load(pb,       __ATOMIC_RELAXED, __HIP_MEMORY_SCOPE_AGENT);
                v5 = __hip_atomic_load(pb + 1,   __ATOMIC_RELAXED, __HIP_MEMORY_SCOPE_AGENT);
                v6 = __hip_atomic_load(pb + 128, __ATOMIC_RELAXED, __HIP_MEMORY_SCOPE_AGENT);
                v7 = __hip_atomic_load(pb + 129, __ATOMIC_RELAXED, __HIP_MEMORY_SCOPE_AGENT);
                uint bad = ((uint)(v0 >> 32) ^ tg) | ((uint)(v1 >> 32) ^ tg)
                         | ((uint)(v2 >> 32) ^ tg) | ((uint)(v3 >> 32) ^ tg)
                         | ((uint)(v4 >> 32) ^ tg) | ((uint)(v5 >> 32) ^ tg)
                         | ((uint)(v6 >> 32) ^ tg) | ((uint)(v7 >> 32) ^ tg);
                if (!bad || --cap == 0) break;
                __builtin_amdgcn_s_sleep(1);
            }
            *(u64t*)&hs16[w * 256 + ((2 * l) ^ swz)]
                = (v0 & 0xffffffffull) | (v1 << 32);
            *(u64t*)&hs16[w * 256 + ((2 * l + 128) ^ swz)]
                = (v2 & 0xffffffffull) | (v3 << 32);
            *(u64t*)&hs16[(w + 8) * 256 + ((2 * l) ^ swz)]
                = (v4 & 0xffffffffull) | (v5 << 32);
            *(u64t*)&hs16[(w + 8) * 256 + ((2 * l + 128) ^ swz)]
                = (v6 & 0xffffffffull) | (v7 << 32);
        }
        __syncthreads();

        // ---- MFMA: 16 rows x 16 sample-columns, K=512, 2 acc chains ----
        f32x4 acc0 = {0.f, 0.f, 0.f, 0.f}, acc1 = {0.f, 0.f, 0.f, 0.f};
        {
            const int smswz = (sm & 7) << 2;
            const int bbase = sm * 256;
            #pragma unroll
            for (int kk = 0; kk < 16; kk += 2) {
                U128H b0, b1;
                b0.u = *(const uint4*)&hs16[bbase + ((kk * 16 + ks * 4) ^ smswz)];
                b1.u = *(const uint4*)&hs16[bbase + (((kk + 1) * 16 + ks * 4) ^ smswz)];
                acc0 = __builtin_amdgcn_mfma_f32_16x16x32_f16(wf[kk],     b0.h, acc0, 0, 0, 0);
                acc1 = __builtin_amdgcn_mfma_f32_16x16x32_f16(wf[kk + 1], b1.h, acc1, 0, 0, 0);
            }
        }

        // ---- in-lane gates + state update + DIRECT tagged-unit store ----
        {
            float xv = xsm[sm];
            int   r0 = w * 16 + ks * 4;
            float p0 = fmaf(xv, wih_s[r0 + 0], (acc0[0] + acc1[0]) + bsum_s[r0 + 0]);
            float p1 = fmaf(xv, wih_s[r0 + 1], (acc0[1] + acc1[1]) + bsum_s[r0 + 1]);
            float p2 = fmaf(xv, wih_s[r0 + 2], (acc0[2] + acc1[2]) + bsum_s[r0 + 2]);
            float p3 = fmaf(xv, wih_s[r0 + 3], (acc0[3] + acc1[3]) + bsum_s[r0 + 3]);
            float iv = 1.f / (1.f + __expf(-p0));
            float fv = 1.f / (1.f + __expf(-p1));
            float gv = 1.f - 2.f / (__expf(2.f * p2) + 1.f);
            float ov = 1.f / (1.f + __expf(-p3));
            float cn = fmaf(fv, creg, iv * gv);
            float hn = ov * (1.f - 2.f / (__expf(2.f * cn) + 1.f));
            bool  mk = mkm[sm] > 0.f;
            creg = mk ? cn : creg;
            hreg = mk ? hn : hreg;

            // pair lanes (ks, ks^1) differ by lane bit 4: compose fp16 dword
            U32H z; z.h.x = (_Float16)hreg; z.h.y = (_Float16)0.f;
            uint myb = z.u & 0xffffu;
            uint pb16 = (uint)__shfl_xor((int)myb, 16, 64);
            if (t + 1 < glenA) {
                if (!(ks & 1)) {
                    u64t val = (u64t)(myb | (pb16 << 16))
                             | ((u64t)(uint)(t + 1) << 32);
                    __hip_atomic_store(
                        &gx[(size_t)((t + 1) & 1) * 65536 + (size_t)sslot * 256 + myk2],
                        val, __ATOMIC_RELAXED, __HIP_MEMORY_SCOPE_AGENT);
                }
            } else {
                hbuf[(size_t)sslot * HH + jg * JW + jjl] = hreg;   // final h
            }
        }
        __syncthreads();   // LDS WAR: all MFMA reads done before next staging
    }
}

// ---------------- epilogue: logits + masked softmax ----------------
__global__ __launch_bounds__(256) void epi_k(
    const float* __restrict__ hbuf, const float* __restrict__ fcWT,
    const float* __restrict__ fcb, const int* __restrict__ len,
    const int* __restrict__ perm, float* __restrict__ out)
{
    __shared__ float hb[HH];
    __shared__ float lg[TT];
    __shared__ float red[4];
    const int slot = blockIdx.x, tid = threadIdx.x;
    const int ob = perm[slot];

    const float* hfin = hbuf + (size_t)slot * HH;
    for (int i = tid; i < HH; i += 256) hb[i] = hfin[i];
    __syncthreads();

    const int t0 = tid * 4;
    float a0 = fcb[t0], a1 = fcb[t0 + 1], a2 = fcb[t0 + 2], a3 = fcb[t0 + 3];
    #pragma unroll 8
    for (int k = 0; k < HH; ++k) {
        float4 w = *(const float4*)&fcWT[k * TT + t0];
        float hv = hb[k];
        a0 += w.x * hv; a1 += w.y * hv; a2 += w.z * hv; a3 += w.w * hv;
    }
    lg[t0] = a0; lg[t0 + 1] = a1; lg[t0 + 2] = a2; lg[t0 + 3] = a3;
    __syncthreads();

    const int L = len[ob];
    float mx = -3.4e38f;
    for (int i = tid; i < L; i += 256) mx = fmaxf(mx, lg[i]);
    for (int o = 32; o > 0; o >>= 1) mx = fmaxf(mx, __shfl_down(mx, o, 64));
    if ((tid & 63) == 0) red[tid >> 6] = mx;
    __syncthreads();
    mx = fmaxf(fmaxf(red[0], red[1]), fmaxf(red[2], red[3]));
    __syncthreads();

    float sm = 0.f;
    for (int i = tid; i < L; i += 256) {
        float e = __expf(lg[i] - mx);
        lg[i] = e;
        sm += e;
    }
    for (int o = 32; o > 0; o >>= 1) sm += __shfl_down(sm, o, 64);
    if ((tid & 63) == 0) red[tid >> 6] = sm;
    __syncthreads();
    sm = red[0] + red[1] + red[2] + red[3];
    float inv = 1.f / sm;

    for (int i = tid; i < TT; i += 256)
        out[ob * TT + i] = (i < L) ? lg[i] * inv : 1.0f;
}

// ---------------- launch ----------------
extern "C" void kernel_launch(void* const* d_in, const int* in_sizes, int n_in,
                              void* d_out, int out_size, void* d_ws, size_t ws_size,
                              hipStream_t stream)
{
    const float* traj = (const float*)d_in[0];
    const float* Wih  = (const float*)d_in[1];
    const float* Whh  = (const float*)d_in[2];
    const float* bih  = (const float*)d_in[3];
    const float* bhh  = (const float*)d_in[4];
    const float* fcW  = (const float*)d_in[5];
    const float* fcb  = (const float*)d_in[6];
    float* out = (float*)d_out;

    uint*  Wpk16 = (uint*)d_ws;                      // 524,288 dw (2MB)
    float* fcWT  = (float*)(Wpk16 + NJ * 8 * 16 * 64 * 4);  // 524,288 fl
    float* bsum  = fcWT + HH * TT;                   // 2,048
    float* hbuf  = bsum + G4;                        // 131,072 (final h)
    u64t*  gx    = (u64t*)(hbuf + BB * HH);          // 131,072 u64 (1MB)
    int*   len   = (int*)(gx + GXN);                 // 256
    int*   perm  = len + BB;                         // 256
    int*   glen  = perm + BB;                        // 32

    prep_k<<<2048, 256, 0, stream>>>(Whh, fcW, bih, bhh, Wpk16, fcWT, bsum, gx);
    lens_k<<<BB, 256, 0, stream>>>(traj, len);
    sort_k<<<1, 256, 0, stream>>>(len, perm, glen);

    {
        const float* traj_l = traj; const float* wih_l = Wih;
        const uint* wpk_l = Wpk16;  const float* bsum_l = bsum;
        float* hbuf_l = hbuf;       u64t* gx_l = gx;
        const int* perm_l = perm;   const int* glen_l = glen;
        void* args[] = { (void*)&traj_l, (void*)&wih_l, (void*)&wpk_l, (void*)&bsum_l,
                         (void*)&hbuf_l, (void*)&gx_l, (void*)&perm_l, (void*)&glen_l };
        (void)hipLaunchCooperativeKernel((const void*)lstm_persist, dim3(256), dim3(512),
                                         args, 0, stream);
    }

    epi_k<<<BB, 256, 0, stream>>>(hbuf, fcWT, fcb, len, perm, out);
}

// Round 14
// 2201.264 us; speedup vs baseline: 1.5090x; 1.5090x over previous
//
#include <hip/hip_runtime.h>

#define TT 1024
#define BB 256
#define HH 512
#define G4 2048
#define NG 32   // sample groups
#define SG 8    // samples per group
#define NJ 16   // wgs (j-slices) per cohort
#define RW 128  // rows per slice = 4 gates * 32 j
#define JW 32   // j per slice
#define GXN 131072  // 2 * 256 * 256 exchange units (8B each)

typedef _Float16 half2v __attribute__((ext_vector_type(2)));
typedef _Float16 half8  __attribute__((ext_vector_type(8)));
typedef float    f32x4  __attribute__((ext_vector_type(4)));
typedef unsigned int uint;
typedef unsigned long long u64t;

union U32H  { uint u; half2v h; };
union U128H { uint4 u; half8 h; };

// ---------------- prep: fp16 W repack into MFMA A-fragments + gx clear ------
// m = jjq*4 + gate (jj-major, gate-minor) so a lane's 4 D-regs are i,f,g,o of ONE jj.
__global__ __launch_bounds__(256) void prep_k(
    const float* __restrict__ Whh, const float* __restrict__ fcW,
    const float* __restrict__ bih, const float* __restrict__ bhh,
    uint* __restrict__ Wpk16, float* __restrict__ fcWT, float* __restrict__ bsum,
    u64t* __restrict__ gx)
{
    int n  = blockDim.x * gridDim.x;
    int i0 = blockIdx.x * blockDim.x + threadIdx.x;
    for (int i = i0; i < NJ * 8 * 16 * 64 * 4; i += n) {
        int d  = i & 3;
        int l  = (i >> 2) & 63;
        int kk = (i >> 8) & 15;
        int w  = (i >> 12) & 7;
        int jg = (i >> 15) & 15;
        int m    = l & 15;
        int gate = m & 3, jjq = m >> 2;
        int grow = gate * HH + jg * JW + w * 4 + jjq;
        int k    = kk * 32 + ((l >> 4) & 3) * 8 + 2 * d;
        half2v p;
        p.x = (_Float16)Whh[grow * HH + k];
        p.y = (_Float16)Whh[grow * HH + k + 1];
        U32H x; x.h = p;
        Wpk16[i] = x.u;
    }
    for (int i = i0; i < HH * TT; i += n) {
        int k = i >> 10, t = i & (TT - 1);
        fcWT[i] = fcW[t * HH + k];
    }
    for (int i = i0; i < G4; i += n) bsum[i] = bih[i] + bhh[i];
    for (int i = i0; i < GXN; i += n) gx[i] = 0;   // clear tags EVERY launch
}

// ---------------- lengths ----------------
__global__ __launch_bounds__(256) void lens_k(const float* __restrict__ traj,
                                              int* __restrict__ len)
{
    int b = blockIdx.x;
    int cnt = 0;
    for (int i = threadIdx.x; i < TT; i += 256)
        cnt += (traj[b * TT + i] != -1.0f) ? 1 : 0;
    for (int o = 32; o > 0; o >>= 1) cnt += __shfl_down(cnt, o, 64);
    __shared__ int s4[4];
    if ((threadIdx.x & 63) == 0) s4[threadIdx.x >> 6] = cnt;
    __syncthreads();
    if (threadIdx.x == 0) len[b] = s4[0] + s4[1] + s4[2] + s4[3];
}

// ---------------- sort by length (descending), group maxes ----------------
__global__ __launch_bounds__(256) void sort_k(const int* __restrict__ len,
                                              int* __restrict__ perm,
                                              int* __restrict__ glen)
{
    __shared__ int L[256];
    __shared__ int P[256];
    int tid = threadIdx.x;
    L[tid] = len[tid];
    __syncthreads();
    int l = L[tid], r = 0;
    for (int b = 0; b < 256; ++b) {
        int lb = L[b];
        r += (lb > l) || (lb == l && b < tid);
    }
    P[r] = tid;
    __syncthreads();
    perm[tid] = P[tid];
    if (tid < NG) glen[tid] = L[P[tid * SG]];
}

// ---------------- persistent LSTM: tagged units, calibrated first poll ------
// grid 256 = 16 slots x 16 j-slices. Slot p serves groups gA=p (cols 0-7) and
// gB=31-p (cols 8-15) in one MFMA pass. Exchange unit = {2 fp16 h | tag} u64,
// agent-scope atomics; coalesced composer stores; first poll delayed to hit.
__global__ __launch_bounds__(512, 2) void lstm_persist(
    const float* __restrict__ traj, const float* __restrict__ Wih,
    const uint* __restrict__ Wpk16, const float* __restrict__ bsum,
    float* __restrict__ hbuf,                 // [BB][HH] final h only
    u64t* __restrict__ gx,                    // [2][256][256] tagged units
    const int* __restrict__ perm, const int* __restrict__ glen)
{
    __shared__ __align__(16) float smem[23040];   // 90KB -> 1 wg/CU
    __shared__ float xsm[16], mkm[16];
    __shared__ int   osm[16];
    __shared__ float wih_s[RW], bsum_s[RW];

    uint*     const hs16 = (uint*)smem;               // 16 x 256 dw
    _Float16* const pack = (_Float16*)(smem + 4096);  // [16][36] fp16

    const int wg   = blockIdx.x;
    const int slot = wg & 15;
    const int jg   = wg >> 4;
    const int tid  = threadIdx.x;
    const int gA = slot, gB = 31 - slot;

    if (tid < 16)
        osm[tid] = perm[(tid < 8) ? (gA * SG + tid) : (gB * SG + tid - 8)];
    if (tid < RW) {
        int m = tid & 15;
        int grow = (m & 3) * HH + jg * JW + (tid >> 4) * 4 + (m >> 2);
        wih_s[tid]  = Wih[grow];
        bsum_s[tid] = bsum[grow];
    }
    const int glenA = glen[gA];

    // W A-fragments -> registers
    half8 wf[16];
    {
        const int w0 = tid >> 6, l0 = tid & 63;
        const uint4* wp = (const uint4*)Wpk16;
        const int base = (jg * 8 + w0) * 1024 + l0;
        #pragma unroll
        for (int kk = 0; kk < 16; ++kk) {
            U128H u; u.u = wp[base + kk * 64];
            wf[kk] = u.h;
        }
    }

    // lane roles
    const int w   = tid >> 6;       // wave id
    const int l   = tid & 63;
    const int sm  = l & 15;         // MFMA column = sample slot (A:0-7, B:8-15)
    const int ks  = (l >> 4) & 3;
    const int jjl = w * 4 + ks;
    const int sslot = (sm < 8) ? (gA * SG + sm) : (gB * SG + sm - 8);
    const int csA = gA * SG + w;    // staging samples (consumer role)
    const int csB = gB * SG + w;
    const int swz = (w & 7) << 2;

    float creg = 0.f, hreg = 0.f;
    __syncthreads();

    for (int t = 0; t < glenA; ++t) {
        // ---- early x loads (complete under the poll) ----
        if (tid < 16) {
            float v = traj[(size_t)osm[tid] * TT + t];
            xsm[tid] = v;
            mkm[tid] = (v != -1.0f) ? 1.f : 0.f;
        }
        // ---- stage h(t) -> LDS (fp16 pairs, XOR-swizzled dword pairs) ----
        if (t == 0) {
            u64t z = 0;
            *(u64t*)&hs16[w * 256 + ((2 * l) ^ swz)]             = z;
            *(u64t*)&hs16[w * 256 + ((2 * l + 128) ^ swz)]       = z;
            *(u64t*)&hs16[(w + 8) * 256 + ((2 * l) ^ swz)]       = z;
            *(u64t*)&hs16[(w + 8) * 256 + ((2 * l + 128) ^ swz)] = z;
        } else {
            u64t* base = gx + (size_t)(t & 1) * 65536;
            u64t* pa = base + (size_t)csA * 256 + 2 * l;
            u64t* pb = base + (size_t)csB * 256 + 2 * l;
            const uint tg = (uint)t;
            u64t v0, v1, v2, v3, v4, v5, v6, v7;
            int cap = 1 << 22;           // bounded spin: never hang
            // calibrated delay: let producer stores land so round 1 HITS
            __builtin_amdgcn_s_sleep(6);
            for (;;) {
                v0 = __hip_atomic_load(pa,       __ATOMIC_RELAXED, __HIP_MEMORY_SCOPE_AGENT);
                v1 = __hip_atomic_load(pa + 1,   __ATOMIC_RELAXED, __HIP_MEMORY_SCOPE_AGENT);
                v2 = __hip_atomic_load(pa + 128, __ATOMIC_RELAXED, __HIP_MEMORY_SCOPE_AGENT);
                v3 = __hip_atomic_load(pa + 129, __ATOMIC_RELAXED, __HIP_MEMORY_SCOPE_AGENT);
                v4 = __hip_atomic_load(pb,       __ATOMIC_RELAXED, __HIP_MEMORY_SCOPE_AGENT);
                v5 = __hip_atomic_load(pb + 1,   __ATOMIC_RELAXED, __HIP_MEMORY_SCOPE_AGENT);
                v6 = __hip_atomic_load(pb + 128, __ATOMIC_RELAXED, __HIP_MEMORY_SCOPE_AGENT);
                v7 = __hip_atomic_load(pb + 129, __ATOMIC_RELAXED, __HIP_MEMORY_SCOPE_AGENT);
                uint bad = ((uint)(v0 >> 32) ^ tg) | ((uint)(v1 >> 32) ^ tg)
                         | ((uint)(v2 >> 32) ^ tg) | ((uint)(v3 >> 32) ^ tg)
                         | ((uint)(v4 >> 32) ^ tg) | ((uint)(v5 >> 32) ^ tg)
                         | ((uint)(v6 >> 32) ^ tg) | ((uint)(v7 >> 32) ^ tg);
                if (!bad || --cap == 0) break;
                __builtin_amdgcn_s_sleep(1);
            }
            *(u64t*)&hs16[w * 256 + ((2 * l) ^ swz)]
                = (v0 & 0xffffffffull) | (v1 << 32);
            *(u64t*)&hs16[w * 256 + ((2 * l + 128) ^ swz)]
                = (v2 & 0xffffffffull) | (v3 << 32);
            *(u64t*)&hs16[(w + 8) * 256 + ((2 * l) ^ swz)]
                = (v4 & 0xffffffffull) | (v5 << 32);
            *(u64t*)&hs16[(w + 8) * 256 + ((2 * l + 128) ^ swz)]
                = (v6 & 0xffffffffull) | (v7 << 32);
        }
        __syncthreads();

        // ---- MFMA: 16 rows x 16 sample-columns, K=512, 2 acc chains ----
        f32x4 acc0 = {0.f, 0.f, 0.f, 0.f}, acc1 = {0.f, 0.f, 0.f, 0.f};
        {
            const int smswz = (sm & 7) << 2;
            const int bbase = sm * 256;
            #pragma unroll
            for (int kk = 0; kk < 16; kk += 2) {
                U128H b0, b1;
                b0.u = *(const uint4*)&hs16[bbase + ((kk * 16 + ks * 4) ^ smswz)];
                b1.u = *(const uint4*)&hs16[bbase + (((kk + 1) * 16 + ks * 4) ^ smswz)];
                acc0 = __builtin_amdgcn_mfma_f32_16x16x32_f16(wf[kk],     b0.h, acc0, 0, 0, 0);
                acc1 = __builtin_amdgcn_mfma_f32_16x16x32_f16(wf[kk + 1], b1.h, acc1, 0, 0, 0);
            }
        }

        // ---- in-lane gates + state update ----
        {
            float xv = xsm[sm];
            int   r0 = w * 16 + ks * 4;
            float p0 = fmaf(xv, wih_s[r0 + 0], (acc0[0] + acc1[0]) + bsum_s[r0 + 0]);
            float p1 = fmaf(xv, wih_s[r0 + 1], (acc0[1] + acc1[1]) + bsum_s[r0 + 1]);
            float p2 = fmaf(xv, wih_s[r0 + 2], (acc0[2] + acc1[2]) + bsum_s[r0 + 2]);
            float p3 = fmaf(xv, wih_s[r0 + 3], (acc0[3] + acc1[3]) + bsum_s[r0 + 3]);
            float iv = 1.f / (1.f + __expf(-p0));
            float fv = 1.f / (1.f + __expf(-p1));
            float gv = 1.f - 2.f / (__expf(2.f * p2) + 1.f);
            float ov = 1.f / (1.f + __expf(-p3));
            float cn = fmaf(fv, creg, iv * gv);
            float hn = ov * (1.f - 2.f / (__expf(2.f * cn) + 1.f));
            bool  mk = mkm[sm] > 0.f;
            creg = mk ? cn : creg;
            hreg = mk ? hn : hreg;
            pack[sm * 36 + jjl] = (_Float16)hreg;
            if (t == glenA - 1)
                hbuf[(size_t)sslot * HH + jg * JW + jjl] = hreg;
        }
        __syncthreads();   // pack visible to composer threads

        // ---- produce tagged units for h(t+1): coalesced 8B stores ----
        if (t + 1 < glenA && tid < 256) {
            int s = tid >> 4, u = tid & 15;
            int k2 = jg * 16 + u;
            uint d = *(const uint*)&pack[s * 36 + u * 2];
            int ss = (s < 8) ? (gA * SG + s) : (gB * SG + s - 8);
            u64t val = (u64t)d | ((u64t)(uint)(t + 1) << 32);
            __hip_atomic_store(&gx[(size_t)((t + 1) & 1) * 65536 + (size_t)ss * 256 + k2],
                               val, __ATOMIC_RELAXED, __HIP_MEMORY_SCOPE_AGENT);
        }
    }
}

// ---------------- epilogue: logits + masked softmax ----------------
__global__ __launch_bounds__(256) void epi_k(
    const float* __restrict__ hbuf, const float* __restrict__ fcWT,
    const float* __restrict__ fcb, const int* __restrict__ len,
    const int* __restrict__ perm, float* __restrict__ out)
{
    __shared__ float hb[HH];
    __shared__ float lg[TT];
    __shared__ float red[4];
    const int slot = blockIdx.x, tid = threadIdx.x;
    const int ob = perm[slot];

    const float* hfin = hbuf + (size_t)slot * HH;
    for (int i = tid; i < HH; i += 256) hb[i] = hfin[i];
    __syncthreads();

    const int t0 = tid * 4;
    float a0 = fcb[t0], a1 = fcb[t0 + 1], a2 = fcb[t0 + 2], a3 = fcb[t0 + 3];
    #pragma unroll 8
    for (int k = 0; k < HH; ++k) {
        float4 w = *(const float4*)&fcWT[k * TT + t0];
        float hv = hb[k];
        a0 += w.x * hv; a1 += w.y * hv; a2 += w.z * hv; a3 += w.w * hv;
    }
    lg[t0] = a0; lg[t0 + 1] = a1; lg[t0 + 2] = a2; lg[t0 + 3] = a3;
    __syncthreads();

    const int L = len[ob];
    float mx = -3.4e38f;
    for (int i = tid; i < L; i += 256) mx = fmaxf(mx, lg[i]);
    for (int o = 32; o > 0; o >>= 1) mx = fmaxf(mx, __shfl_down(mx, o, 64));
    if ((tid & 63) == 0) red[tid >> 6] = mx;
    __syncthreads();
    mx = fmaxf(fmaxf(red[0], red[1]), fmaxf(red[2], red[3]));
    __syncthreads();

    float sm = 0.f;
    for (int i = tid; i < L; i += 256) {
        float e = __expf(lg[i] - mx);
        lg[i] = e;
        sm += e;
    }
    for (int o = 32; o > 0; o >>= 1) sm += __shfl_down(sm, o, 64);
    if ((tid & 63) == 0) red[tid >> 6] = sm;
    __syncthreads();
    sm = red[0] + red[1] + red[2] + red[3];
    float inv = 1.f / sm;

    for (int i = tid; i < TT; i += 256)
        out[ob * TT + i] = (i < L) ? lg[i] * inv : 1.0f;
}

// ---------------- launch ----------------
extern "C" void kernel_launch(void* const* d_in, const int* in_sizes, int n_in,
                              void* d_out, int out_size, void* d_ws, size_t ws_size,
                              hipStream_t stream)
{
    const float* traj = (const float*)d_in[0];
    const float* Wih  = (const float*)d_in[1];
    const float* Whh  = (const float*)d_in[2];
    const float* bih  = (const float*)d_in[3];
    const float* bhh  = (const float*)d_in[4];
    const float* fcW  = (const float*)d_in[5];
    const float* fcb  = (const float*)d_in[6];
    float* out = (float*)d_out;

    uint*  Wpk16 = (uint*)d_ws;                      // 524,288 dw (2MB)
    float* fcWT  = (float*)(Wpk16 + NJ * 8 * 16 * 64 * 4);  // 524,288 fl
    float* bsum  = fcWT + HH * TT;                   // 2,048
    float* hbuf  = bsum + G4;                        // 131,072 (final h)
    u64t*  gx    = (u64t*)(hbuf + BB * HH);          // 131,072 u64 (1MB)
    int*   len   = (int*)(gx + GXN);                 // 256
    int*   perm  = len + BB;                         // 256
    int*   glen  = perm + BB;                        // 32

    prep_k<<<2048, 256, 0, stream>>>(Whh, fcW, bih, bhh, Wpk16, fcWT, bsum, gx);
    lens_k<<<BB, 256, 0, stream>>>(traj, len);
    sort_k<<<1, 256, 0, stream>>>(len, perm, glen);

    {
        const float* traj_l = traj; const float* wih_l = Wih;
        const uint* wpk_l = Wpk16;  const float* bsum_l = bsum;
        float* hbuf_l = hbuf;       u64t* gx_l = gx;
        const int* perm_l = perm;   const int* glen_l = glen;
        void* args[] = { (void*)&traj_l, (void*)&wih_l, (void*)&wpk_l, (void*)&bsum_l,
                         (void*)&hbuf_l, (void*)&gx_l, (void*)&perm_l, (void*)&glen_l };
        (void)hipLaunchCooperativeKernel((const void*)lstm_persist, dim3(256), dim3(512),
                                         args, 0, stream);
    }

    epi_k<<<BB, 256, 0, stream>>>(hbuf, fcWT, fcb, len, perm, out);
}

// Round 15
// 2000.364 us; speedup vs baseline: 1.6605x; 1.1004x over previous
//
#include <hip/hip_runtime.h>

#define TT 1024
#define BB 256
#define HH 512
#define G4 2048
#define NG 32   // sample groups
#define SG 8    // samples per group
#define NJ 16   // wgs (j-slices) per cohort
#define RW 128  // rows per slice = 4 gates * 32 j
#define JW 32   // j per slice
#define GXN 131072  // 2 * 256 * 256 exchange units (8B each)

typedef _Float16 half2v __attribute__((ext_vector_type(2)));
typedef _Float16 half8  __attribute__((ext_vector_type(8)));
typedef float    f32x4  __attribute__((ext_vector_type(4)));
typedef unsigned int uint;
typedef unsigned long long u64t;

union U32H  { uint u; half2v h; };
union U128H { uint4 u; half8 h; };

// ---------------- prep: fp16 W repack into MFMA A-fragments + gx clear ------
// m = jjq*4 + gate (jj-major, gate-minor) so a lane's 4 D-regs are i,f,g,o of ONE jj.
__global__ __launch_bounds__(256) void prep_k(
    const float* __restrict__ Whh, const float* __restrict__ fcW,
    const float* __restrict__ bih, const float* __restrict__ bhh,
    uint* __restrict__ Wpk16, float* __restrict__ fcWT, float* __restrict__ bsum,
    u64t* __restrict__ gx)
{
    int n  = blockDim.x * gridDim.x;
    int i0 = blockIdx.x * blockDim.x + threadIdx.x;
    for (int i = i0; i < NJ * 8 * 16 * 64 * 4; i += n) {
        int d  = i & 3;
        int l  = (i >> 2) & 63;
        int kk = (i >> 8) & 15;
        int w  = (i >> 12) & 7;
        int jg = (i >> 15) & 15;
        int m    = l & 15;
        int gate = m & 3, jjq = m >> 2;
        int grow = gate * HH + jg * JW + w * 4 + jjq;
        int k    = kk * 32 + ((l >> 4) & 3) * 8 + 2 * d;
        half2v p;
        p.x = (_Float16)Whh[grow * HH + k];
        p.y = (_Float16)Whh[grow * HH + k + 1];
        U32H x; x.h = p;
        Wpk16[i] = x.u;
    }
    for (int i = i0; i < HH * TT; i += n) {
        int k = i >> 10, t = i & (TT - 1);
        fcWT[i] = fcW[t * HH + k];
    }
    for (int i = i0; i < G4; i += n) bsum[i] = bih[i] + bhh[i];
    for (int i = i0; i < GXN; i += n) gx[i] = 0;   // clear tags EVERY launch
}

// ---------------- lengths ----------------
__global__ __launch_bounds__(256) void lens_k(const float* __restrict__ traj,
                                              int* __restrict__ len)
{
    int b = blockIdx.x;
    int cnt = 0;
    for (int i = threadIdx.x; i < TT; i += 256)
        cnt += (traj[b * TT + i] != -1.0f) ? 1 : 0;
    for (int o = 32; o > 0; o >>= 1) cnt += __shfl_down(cnt, o, 64);
    __shared__ int s4[4];
    if ((threadIdx.x & 63) == 0) s4[threadIdx.x >> 6] = cnt;
    __syncthreads();
    if (threadIdx.x == 0) len[b] = s4[0] + s4[1] + s4[2] + s4[3];
}

// ---------------- sort by length (descending), group maxes ----------------
__global__ __launch_bounds__(256) void sort_k(const int* __restrict__ len,
                                              int* __restrict__ perm,
                                              int* __restrict__ glen)
{
    __shared__ int L[256];
    __shared__ int P[256];
    int tid = threadIdx.x;
    L[tid] = len[tid];
    __syncthreads();
    int l = L[tid], r = 0;
    for (int b = 0; b < 256; ++b) {
        int lb = L[b];
        r += (lb > l) || (lb == l && b < tid);
    }
    P[r] = tid;
    __syncthreads();
    perm[tid] = P[tid];
    if (tid < NG) glen[tid] = L[P[tid * SG]];
}

// ---------------- persistent LSTM: tagged units + tail-gated B exchange ----
// grid 256 = 16 slots x 16 j-slices. Slot p serves groups gA=p (cols 0-7) and
// gB=31-p (cols 8-15) in one MFMA pass. Exchange unit = {2 fp16 h | tag} u64,
// agent-scope atomics; after t>=glenB the frozen B half is neither produced
// nor polled (LDS holds h(glenB)).
__global__ __launch_bounds__(512, 2) void lstm_persist(
    const float* __restrict__ traj, const float* __restrict__ Wih,
    const uint* __restrict__ Wpk16, const float* __restrict__ bsum,
    float* __restrict__ hbuf,                 // [BB][HH] final h only
    u64t* __restrict__ gx,                    // [2][256][256] tagged units
    const int* __restrict__ perm, const int* __restrict__ glen)
{
    __shared__ __align__(16) float smem[23040];   // 90KB -> 1 wg/CU
    __shared__ float xsm[16], mkm[16];
    __shared__ int   osm[16];
    __shared__ float wih_s[RW], bsum_s[RW];

    uint*     const hs16 = (uint*)smem;               // 16 x 256 dw
    _Float16* const pack = (_Float16*)(smem + 4096);  // [16][36] fp16

    const int wg   = blockIdx.x;
    const int slot = wg & 15;
    const int jg   = wg >> 4;
    const int tid  = threadIdx.x;
    const int gA = slot, gB = 31 - slot;

    if (tid < 16)
        osm[tid] = perm[(tid < 8) ? (gA * SG + tid) : (gB * SG + tid - 8)];
    if (tid < RW) {
        int m = tid & 15;
        int grow = (m & 3) * HH + jg * JW + (tid >> 4) * 4 + (m >> 2);
        wih_s[tid]  = Wih[grow];
        bsum_s[tid] = bsum[grow];
    }
    const int glenA = glen[gA];
    const int glenB = glen[gB];     // <= glenA (sorted desc)

    // W A-fragments -> registers
    half8 wf[16];
    {
        const int w0 = tid >> 6, l0 = tid & 63;
        const uint4* wp = (const uint4*)Wpk16;
        const int base = (jg * 8 + w0) * 1024 + l0;
        #pragma unroll
        for (int kk = 0; kk < 16; ++kk) {
            U128H u; u.u = wp[base + kk * 64];
            wf[kk] = u.h;
        }
    }

    // lane roles
    const int w   = tid >> 6;       // wave id
    const int l   = tid & 63;
    const int sm  = l & 15;         // MFMA column = sample slot (A:0-7, B:8-15)
    const int ks  = (l >> 4) & 3;
    const int jjl = w * 4 + ks;
    const int sslot = (sm < 8) ? (gA * SG + sm) : (gB * SG + sm - 8);
    const int csA = gA * SG + w;    // staging samples (consumer role)
    const int csB = gB * SG + w;
    const int swz = (w & 7) << 2;

    float creg = 0.f, hreg = 0.f;
    __syncthreads();

    for (int t = 0; t < glenA; ++t) {
        // ---- early x loads (complete under the poll) ----
        if (tid < 16) {
            float v = traj[(size_t)osm[tid] * TT + t];
            xsm[tid] = v;
            mkm[tid] = (v != -1.0f) ? 1.f : 0.f;
        }
        // ---- stage h(t) -> LDS (fp16 pairs, XOR-swizzled dword pairs) ----
        if (t == 0) {
            u64t z = 0;
            *(u64t*)&hs16[w * 256 + ((2 * l) ^ swz)]             = z;
            *(u64t*)&hs16[w * 256 + ((2 * l + 128) ^ swz)]       = z;
            *(u64t*)&hs16[(w + 8) * 256 + ((2 * l) ^ swz)]       = z;
            *(u64t*)&hs16[(w + 8) * 256 + ((2 * l + 128) ^ swz)] = z;
        } else {
            const bool withB = (t <= glenB);   // B frozen past glenB
            u64t* base = gx + (size_t)(t & 1) * 65536;
            u64t* pa = base + (size_t)csA * 256 + 2 * l;
            u64t* pb = base + (size_t)csB * 256 + 2 * l;
            const uint tg = (uint)t;
            u64t v0, v1, v2, v3, v4 = 0, v5 = 0, v6 = 0, v7 = 0;
            int cap = 1 << 22;           // bounded spin: never hang
            // calibrated delay: let producer stores land so round 1 HITS
            __builtin_amdgcn_s_sleep(8);
            if (withB) {
                for (;;) {
                    v0 = __hip_atomic_load(pa,       __ATOMIC_RELAXED, __HIP_MEMORY_SCOPE_AGENT);
                    v1 = __hip_atomic_load(pa + 1,   __ATOMIC_RELAXED, __HIP_MEMORY_SCOPE_AGENT);
                    v2 = __hip_atomic_load(pa + 128, __ATOMIC_RELAXED, __HIP_MEMORY_SCOPE_AGENT);
                    v3 = __hip_atomic_load(pa + 129, __ATOMIC_RELAXED, __HIP_MEMORY_SCOPE_AGENT);
                    v4 = __hip_atomic_load(pb,       __ATOMIC_RELAXED, __HIP_MEMORY_SCOPE_AGENT);
                    v5 = __hip_atomic_load(pb + 1,   __ATOMIC_RELAXED, __HIP_MEMORY_SCOPE_AGENT);
                    v6 = __hip_atomic_load(pb + 128, __ATOMIC_RELAXED, __HIP_MEMORY_SCOPE_AGENT);
                    v7 = __hip_atomic_load(pb + 129, __ATOMIC_RELAXED, __HIP_MEMORY_SCOPE_AGENT);
                    uint bad = ((uint)(v0 >> 32) ^ tg) | ((uint)(v1 >> 32) ^ tg)
                             | ((uint)(v2 >> 32) ^ tg) | ((uint)(v3 >> 32) ^ tg)
                             | ((uint)(v4 >> 32) ^ tg) | ((uint)(v5 >> 32) ^ tg)
                             | ((uint)(v6 >> 32) ^ tg) | ((uint)(v7 >> 32) ^ tg);
                    if (!bad || --cap == 0) break;
                    __builtin_amdgcn_s_sleep(1);
                }
            } else {
                for (;;) {
                    v0 = __hip_atomic_load(pa,       __ATOMIC_RELAXED, __HIP_MEMORY_SCOPE_AGENT);
                    v1 = __hip_atomic_load(pa + 1,   __ATOMIC_RELAXED, __HIP_MEMORY_SCOPE_AGENT);
                    v2 = __hip_atomic_load(pa + 128, __ATOMIC_RELAXED, __HIP_MEMORY_SCOPE_AGENT);
                    v3 = __hip_atomic_load(pa + 129, __ATOMIC_RELAXED, __HIP_MEMORY_SCOPE_AGENT);
                    uint bad = ((uint)(v0 >> 32) ^ tg) | ((uint)(v1 >> 32) ^ tg)
                             | ((uint)(v2 >> 32) ^ tg) | ((uint)(v3 >> 32) ^ tg);
                    if (!bad || --cap == 0) break;
                    __builtin_amdgcn_s_sleep(1);
                }
            }
            *(u64t*)&hs16[w * 256 + ((2 * l) ^ swz)]
                = (v0 & 0xffffffffull) | (v1 << 32);
            *(u64t*)&hs16[w * 256 + ((2 * l + 128) ^ swz)]
                = (v2 & 0xffffffffull) | (v3 << 32);
            if (withB) {
                *(u64t*)&hs16[(w + 8) * 256 + ((2 * l) ^ swz)]
                    = (v4 & 0xffffffffull) | (v5 << 32);
                *(u64t*)&hs16[(w + 8) * 256 + ((2 * l + 128) ^ swz)]
                    = (v6 & 0xffffffffull) | (v7 << 32);
            }
            // !withB: B half keeps h(glenB) — frozen and correct
        }
        __syncthreads();

        // ---- MFMA: 16 rows x 16 sample-columns, K=512, 2 acc chains ----
        f32x4 acc0 = {0.f, 0.f, 0.f, 0.f}, acc1 = {0.f, 0.f, 0.f, 0.f};
        {
            const int smswz = (sm & 7) << 2;
            const int bbase = sm * 256;
            #pragma unroll
            for (int kk = 0; kk < 16; kk += 2) {
                U128H b0, b1;
                b0.u = *(const uint4*)&hs16[bbase + ((kk * 16 + ks * 4) ^ smswz)];
                b1.u = *(const uint4*)&hs16[bbase + (((kk + 1) * 16 + ks * 4) ^ smswz)];
                acc0 = __builtin_amdgcn_mfma_f32_16x16x32_f16(wf[kk],     b0.h, acc0, 0, 0, 0);
                acc1 = __builtin_amdgcn_mfma_f32_16x16x32_f16(wf[kk + 1], b1.h, acc1, 0, 0, 0);
            }
        }

        // ---- in-lane gates + state update ----
        {
            float xv = xsm[sm];
            int   r0 = w * 16 + ks * 4;
            float p0 = fmaf(xv, wih_s[r0 + 0], (acc0[0] + acc1[0]) + bsum_s[r0 + 0]);
            float p1 = fmaf(xv, wih_s[r0 + 1], (acc0[1] + acc1[1]) + bsum_s[r0 + 1]);
            float p2 = fmaf(xv, wih_s[r0 + 2], (acc0[2] + acc1[2]) + bsum_s[r0 + 2]);
            float p3 = fmaf(xv, wih_s[r0 + 3], (acc0[3] + acc1[3]) + bsum_s[r0 + 3]);
            float iv = 1.f / (1.f + __expf(-p0));
            float fv = 1.f / (1.f + __expf(-p1));
            float gv = 1.f - 2.f / (__expf(2.f * p2) + 1.f);
            float ov = 1.f / (1.f + __expf(-p3));
            float cn = fmaf(fv, creg, iv * gv);
            float hn = ov * (1.f - 2.f / (__expf(2.f * cn) + 1.f));
            bool  mk = mkm[sm] > 0.f;
            creg = mk ? cn : creg;
            hreg = mk ? hn : hreg;
            pack[sm * 36 + jjl] = (_Float16)hreg;
            if (t == glenA - 1)
                hbuf[(size_t)sslot * HH + jg * JW + jjl] = hreg;
        }
        __syncthreads();   // pack visible to composer threads

        // ---- produce tagged units for h(t+1): coalesced 8B stores ----
        // B producers stop after t+1 > glenB (consumers stop polling then too)
        if (t + 1 < glenA && tid < 256) {
            int s = tid >> 4, u = tid & 15;
            if (s < 8 || t + 1 <= glenB) {
                int k2 = jg * 16 + u;
                uint d = *(const uint*)&pack[s * 36 + u * 2];
                int ss = (s < 8) ? (gA * SG + s) : (gB * SG + s - 8);
                u64t val = (u64t)d | ((u64t)(uint)(t + 1) << 32);
                __hip_atomic_store(&gx[(size_t)((t + 1) & 1) * 65536 + (size_t)ss * 256 + k2],
                                   val, __ATOMIC_RELAXED, __HIP_MEMORY_SCOPE_AGENT);
            }
        }
    }
}

// ---------------- epilogue: logits + masked softmax ----------------
__global__ __launch_bounds__(256) void epi_k(
    const float* __restrict__ hbuf, const float* __restrict__ fcWT,
    const float* __restrict__ fcb, const int* __restrict__ len,
    const int* __restrict__ perm, float* __restrict__ out)
{
    __shared__ float hb[HH];
    __shared__ float lg[TT];
    __shared__ float red[4];
    const int slot = blockIdx.x, tid = threadIdx.x;
    const int ob = perm[slot];

    const float* hfin = hbuf + (size_t)slot * HH;
    for (int i = tid; i < HH; i += 256) hb[i] = hfin[i];
    __syncthreads();

    const int t0 = tid * 4;
    float a0 = fcb[t0], a1 = fcb[t0 + 1], a2 = fcb[t0 + 2], a3 = fcb[t0 + 3];
    #pragma unroll 8
    for (int k = 0; k < HH; ++k) {
        float4 w = *(const float4*)&fcWT[k * TT + t0];
        float hv = hb[k];
        a0 += w.x * hv; a1 += w.y * hv; a2 += w.z * hv; a3 += w.w * hv;
    }
    lg[t0] = a0; lg[t0 + 1] = a1; lg[t0 + 2] = a2; lg[t0 + 3] = a3;
    __syncthreads();

    const int L = len[ob];
    float mx = -3.4e38f;
    for (int i = tid; i < L; i += 256) mx = fmaxf(mx, lg[i]);
    for (int o = 32; o > 0; o >>= 1) mx = fmaxf(mx, __shfl_down(mx, o, 64));
    if ((tid & 63) == 0) red[tid >> 6] = mx;
    __syncthreads();
    mx = fmaxf(fmaxf(red[0], red[1]), fmaxf(red[2], red[3]));
    __syncthreads();

    float sm = 0.f;
    for (int i = tid; i < L; i += 256) {
        float e = __expf(lg[i] - mx);
        lg[i] = e;
        sm += e;
    }
    for (int o = 32; o > 0; o >>= 1) sm += __shfl_down(sm, o, 64);
    if ((tid & 63) == 0) red[tid >> 6] = sm;
    __syncthreads();
    sm = red[0] + red[1] + red[2] + red[3];
    float inv = 1.f / sm;

    for (int i = tid; i < TT; i += 256)
        out[ob * TT + i] = (i < L) ? lg[i] * inv : 1.0f;
}

// ---------------- launch ----------------
extern "C" void kernel_launch(void* const* d_in, const int* in_sizes, int n_in,
                              void* d_out, int out_size, void* d_ws, size_t ws_size,
                              hipStream_t stream)
{
    const float* traj = (const float*)d_in[0];
    const float* Wih  = (const float*)d_in[1];
    const float* Whh  = (const float*)d_in[2];
    const float* bih  = (const float*)d_in[3];
    const float* bhh  = (const float*)d_in[4];
    const float* fcW  = (const float*)d_in[5];
    const float* fcb  = (const float*)d_in[6];
    float* out = (float*)d_out;

    uint*  Wpk16 = (uint*)d_ws;                      // 524,288 dw (2MB)
    float* fcWT  = (float*)(Wpk16 + NJ * 8 * 16 * 64 * 4);  // 524,288 fl
    float* bsum  = fcWT + HH * TT;                   // 2,048
    float* hbuf  = bsum + G4;                        // 131,072 (final h)
    u64t*  gx    = (u64t*)(hbuf + BB * HH);          // 131,072 u64 (1MB)
    int*   len   = (int*)(gx + GXN);                 // 256
    int*   perm  = len + BB;                         // 256
    int*   glen  = perm + BB;                        // 32

    prep_k<<<2048, 256, 0, stream>>>(Whh, fcW, bih, bhh, Wpk16, fcWT, bsum, gx);
    lens_k<<<BB, 256, 0, stream>>>(traj, len);
    sort_k<<<1, 256, 0, stream>>>(len, perm, glen);

    {
        const float* traj_l = traj; const float* wih_l = Wih;
        const uint* wpk_l = Wpk16;  const float* bsum_l = bsum;
        float* hbuf_l = hbuf;       u64t* gx_l = gx;
        const int* perm_l = perm;   const int* glen_l = glen;
        void* args[] = { (void*)&traj_l, (void*)&wih_l, (void*)&wpk_l, (void*)&bsum_l,
                         (void*)&hbuf_l, (void*)&gx_l, (void*)&perm_l, (void*)&glen_l };
        (void)hipLaunchCooperativeKernel((const void*)lstm_persist, dim3(256), dim3(512),
                                         args, 0, stream);
    }

    epi_k<<<BB, 256, 0, stream>>>(hbuf, fcWT, fcb, len, perm, out);
}